// Round 1
// baseline (38835.745 us; speedup 1.0000x reference)
//
#include <hip/hip_runtime.h>
#include <stdint.h>

#define B_  256
#define T_  512
#define IN_ 64
#define H_  512
#define G4_ 2048
#define NC_ 64
#define H2_ 256
#define CH_ 64     // timestep chunk
#define NG_ 16     // batch groups (16 batch rows each)
#define NS_ 16     // gate slices  (32 h-cols each)

typedef _Float16 f16;
typedef __attribute__((ext_vector_type(4))) _Float16 f16x4;
typedef __attribute__((ext_vector_type(4))) float    f32x4;

__device__ __forceinline__ float sigf(float x) { return 1.0f / (1.0f + __expf(-x)); }

// ---------------- prep kernels ----------------
__global__ void cvt_f32_f16(const float* __restrict__ s, f16* __restrict__ d, int n) {
  int i = blockIdx.x * blockDim.x + threadIdx.x;
  int st = gridDim.x * blockDim.x;
  for (; i < n; i += st) d[i] = (f16)s[i];
}

__global__ void bias_comb(const float* __restrict__ a, const float* __restrict__ b,
                          float* __restrict__ d, int n) {
  int i = blockIdx.x * blockDim.x + threadIdx.x;
  if (i < n) d[i] = a[i] + b[i];
}

// ---------------- gx GEMM:  out[tc][b][g] = A[b][t0+tc][:] . W[g][:] + bias[g] ----------------
// A: [B][T][K] fp16 rows, W: [2048][K] fp16, out: [CH][B][2048] fp16
__global__ __launch_bounds__(256, 2) void gemm_g(
    const f16* __restrict__ A, const f16* __restrict__ W,
    const float* __restrict__ bias, f16* __restrict__ out, int K, int t0) {
  __shared__ f16 As[64][40];
  __shared__ f16 Bs[128][40];
  const int b    = blockIdx.x;
  const int nblk = blockIdx.y;
  const int tid  = threadIdx.x;
  const int lane = tid & 63, wv = tid >> 6;
  const int l15 = lane & 15, hi = lane >> 4;
  const int mbase = (wv >> 1) * 32, nbase = (wv & 1) * 64;

  f32x4 acc[2][4] = {};
  const f16* Ab = A + ((size_t)b * T_ + t0) * K;
  const f16* Wb = W + (size_t)nblk * 128 * K;

  for (int kb = 0; kb < K; kb += 32) {
    {
      const int r = tid >> 2, ko = (tid & 3) * 8;
      *(uint4*)&As[r][ko] = *(const uint4*)(Ab + (size_t)r * K + kb + ko);
    }
    {
      const int r = tid >> 1, ko = (tid & 1) * 16;
      *(uint4*)&Bs[r][ko]     = *(const uint4*)(Wb + (size_t)r * K + kb + ko);
      *(uint4*)&Bs[r][ko + 8] = *(const uint4*)(Wb + (size_t)r * K + kb + ko + 8);
    }
    __syncthreads();
#pragma unroll
    for (int ks = 0; ks < 2; ++ks) {
      const f16x4 a0 = *(const f16x4*)&As[mbase + l15][ks * 16 + 4 * hi];
      const f16x4 a1 = *(const f16x4*)&As[mbase + 16 + l15][ks * 16 + 4 * hi];
#pragma unroll
      for (int nt = 0; nt < 4; ++nt) {
        const f16x4 bf = *(const f16x4*)&Bs[nbase + nt * 16 + l15][ks * 16 + 4 * hi];
        acc[0][nt] = __builtin_amdgcn_mfma_f32_16x16x16f16(a0, bf, acc[0][nt], 0, 0, 0);
        acc[1][nt] = __builtin_amdgcn_mfma_f32_16x16x16f16(a1, bf, acc[1][nt], 0, 0, 0);
      }
    }
    __syncthreads();
  }
#pragma unroll
  for (int mt = 0; mt < 2; ++mt)
#pragma unroll
    for (int nt = 0; nt < 4; ++nt) {
      const int n = nblk * 128 + nbase + nt * 16 + l15;
      const float bv = bias[n];
#pragma unroll
      for (int r = 0; r < 4; ++r) {
        const int ml = mbase + mt * 16 + 4 * hi + r;   // local timestep 0..63
        out[((size_t)ml * B_ + b) * G4_ + n] = (f16)(acc[mt][nt][r] + bv);
      }
    }
}

// ---------------- recurrent scan (one layer, CH_ steps) ----------------
// block (grp,sl): batch rows grp*16..+15, h-cols sl*32..+31 (gate rows {j, j+512, j+1024, j+1536})
__global__ __launch_bounds__(256, 1) void scan_g(
    const f16* __restrict__ gx,    // [CH][B][2048]  (bias folded in)
    const f16* __restrict__ whh,   // [2048][512]
    f16* __restrict__ hbuf,        // [2][B][512]
    float* __restrict__ cst,       // [B][512]
    f16* __restrict__ outseq,      // [B][T][512] or nullptr
    int t0, unsigned* __restrict__ bar) {
  __shared__ f16 ht[16][516];
  __shared__ float gl[16][132];

  const int grp = blockIdx.x >> 4, sl = blockIdx.x & 15;
  const int tid = threadIdx.x;
  const int lane = tid & 63, wv = tid >> 6;
  const int l15 = lane & 15, hi = lane >> 4;

  // preload static W_hh fragments into registers: 2 N-tiles x 32 k-steps
  int gidx[2];
  f16x4 bfr[2][32];
#pragma unroll
  for (int nt = 0; nt < 2; ++nt) {
    const int lg = (wv * 2 + nt) * 16 + l15;                 // local gate 0..127
    const int grow = (lg >> 5) * H_ + sl * 32 + (lg & 31);   // global gate row
    gidx[nt] = grow;
    const f16* wp = whh + (size_t)grow * H_;
#pragma unroll
    for (int ks = 0; ks < 32; ++ks)
      bfr[nt][ks] = *(const f16x4*)(wp + ks * 16 + 4 * hi);
  }

  // each thread owns 2 adjacent (batch,row) cells of the 16x32 state tile
  const int q = tid * 2;
  const int bl = q >> 5;
  const int j0 = q & 31, j1 = j0 + 1;
  const size_t cbase = (size_t)(grp * 16 + bl) * H_ + sl * 32;
  float c0 = 0.f, c1 = 0.f;
  if (t0 != 0) { c0 = cst[cbase + j0]; c1 = cst[cbase + j1]; }

  const int hrow = tid >> 4;
  const int hcol = (tid & 15) * 32;

  for (int it = 0; it < CH_; ++it) {
    const int t = t0 + it;
    const int cur = t & 1;

    // stage h(t-1) tile into LDS
    if (t == 0) {
      uint2 z; z.x = 0u; z.y = 0u;
#pragma unroll
      for (int u = 0; u < 8; ++u) *(uint2*)&ht[hrow][hcol + u * 4] = z;
    } else {
      const f16* hs = hbuf + ((size_t)(cur ^ 1) * B_ + grp * 16 + hrow) * H_ + hcol;
#pragma unroll
      for (int u = 0; u < 8; ++u)
        *(uint2*)&ht[hrow][hcol + u * 4] = *(const uint2*)(hs + u * 4);
    }

    // init accumulators from precomputed gx (bias included)
    f32x4 acc[2];
    {
      const f16* gb = gx + ((size_t)it * B_ + grp * 16) * G4_;
#pragma unroll
      for (int nt = 0; nt < 2; ++nt)
#pragma unroll
        for (int r = 0; r < 4; ++r)
          acc[nt][r] = (float)gb[(size_t)(4 * hi + r) * G4_ + gidx[nt]];
    }
    __syncthreads();

#pragma unroll
    for (int ks = 0; ks < 32; ++ks) {
      const f16x4 a = *(const f16x4*)&ht[l15][ks * 16 + 4 * hi];
      acc[0] = __builtin_amdgcn_mfma_f32_16x16x16f16(a, bfr[0][ks], acc[0], 0, 0, 0);
      acc[1] = __builtin_amdgcn_mfma_f32_16x16x16f16(a, bfr[1][ks], acc[1], 0, 0, 0);
    }

    __syncthreads();
#pragma unroll
    for (int nt = 0; nt < 2; ++nt) {
      const int col = (wv * 2 + nt) * 16 + l15;
#pragma unroll
      for (int r = 0; r < 4; ++r) gl[4 * hi + r][col] = acc[nt][r];
    }
    __syncthreads();

    const float gi0 = gl[bl][j0],      gi1 = gl[bl][j1];
    const float gf0 = gl[bl][32 + j0], gf1 = gl[bl][32 + j1];
    const float gg0 = gl[bl][64 + j0], gg1 = gl[bl][64 + j1];
    const float go0 = gl[bl][96 + j0], go1 = gl[bl][96 + j1];
    c0 = sigf(gf0) * c0 + sigf(gi0) * tanhf(gg0);
    c1 = sigf(gf1) * c1 + sigf(gi1) * tanhf(gg1);
    const float h0 = sigf(go0) * tanhf(c0);
    const float h1 = sigf(go1) * tanhf(c1);
    const f16 h0h = (f16)h0, h1h = (f16)h1;
    f16* hw = hbuf + (size_t)cur * B_ * H_ + cbase;
    hw[j0] = h0h; hw[j1] = h1h;
    if (outseq) {
      f16* ow = outseq + ((size_t)(grp * 16 + bl) * T_ + t) * H_ + sl * 32;
      ow[j0] = h0h; ow[j1] = h1h;
    }
    if (it == CH_ - 1) { cst[cbase + j0] = c0; cst[cbase + j1] = c1; }

    // 16-WG group barrier (monotonic counter, device scope)
    __threadfence();
    __syncthreads();
    if (tid == 0) {
      __hip_atomic_fetch_add(&bar[grp], 1u, __ATOMIC_RELEASE, __HIP_MEMORY_SCOPE_AGENT);
      const unsigned tgt = (unsigned)(it + 1) * NS_;
      while (__hip_atomic_load(&bar[grp], __ATOMIC_ACQUIRE, __HIP_MEMORY_SCOPE_AGENT) < tgt)
        __builtin_amdgcn_s_sleep(1);
    }
    __syncthreads();
  }
}

// ---------------- MLP head ----------------
__global__ void head_g(const f16* __restrict__ h1, const float* __restrict__ w1,
                       const float* __restrict__ b1, const float* __restrict__ w2,
                       const float* __restrict__ b2, float* __restrict__ out) {
  __shared__ float ft[512];
  __shared__ float hm[256];
  const int b = blockIdx.x, tid = threadIdx.x;
  ft[tid * 2]     = (float)h1[(size_t)b * H_ + tid * 2];
  ft[tid * 2 + 1] = (float)h1[(size_t)b * H_ + tid * 2 + 1];
  __syncthreads();
  {
    float d = b1[tid];
    const float* wr = w1 + (size_t)tid * H_;
#pragma unroll 8
    for (int k = 0; k < H_; ++k) d += ft[k] * wr[k];
    hm[tid] = fmaxf(d, 0.f);
  }
  __syncthreads();
  if (tid < NC_) {
    float d = b2[tid];
    const float* wr = w2 + (size_t)tid * H2_;
#pragma unroll 8
    for (int k = 0; k < H2_; ++k) d += hm[k] * wr[k];
    out[(size_t)b * NC_ + tid] = d;
  }
}

// ---------------- launcher ----------------
extern "C" void kernel_launch(void* const* d_in, const int* in_sizes, int n_in,
                              void* d_out, int out_size, void* d_ws, size_t ws_size,
                              hipStream_t stream) {
  const float* x     = (const float*)d_in[0];
  const float* w_ih0 = (const float*)d_in[1];
  const float* w_hh0 = (const float*)d_in[2];
  const float* b_ih0 = (const float*)d_in[3];
  const float* b_hh0 = (const float*)d_in[4];
  const float* w_ih1 = (const float*)d_in[5];
  const float* w_hh1 = (const float*)d_in[6];
  const float* b_ih1 = (const float*)d_in[7];
  const float* b_hh1 = (const float*)d_in[8];
  const float* w1    = (const float*)d_in[9];
  const float* b1    = (const float*)d_in[10];
  const float* w2    = (const float*)d_in[11];
  const float* b2    = (const float*)d_in[12];
  float* out = (float*)d_out;

  char* p = (char*)d_ws;
  auto alloc = [&](size_t bytes) { char* r = p; p += (bytes + 255) & ~(size_t)255; return r; };
  f16*   gxbuf = (f16*)alloc((size_t)CH_ * B_ * G4_ * 2);
  f16*   out0  = (f16*)alloc((size_t)B_ * T_ * H_ * 2);
  f16*   x16   = (f16*)alloc((size_t)B_ * T_ * IN_ * 2);
  f16*   wih0h = (f16*)alloc((size_t)G4_ * IN_ * 2);
  f16*   whh0h = (f16*)alloc((size_t)G4_ * H_ * 2);
  f16*   wih1h = (f16*)alloc((size_t)G4_ * H_ * 2);
  f16*   whh1h = (f16*)alloc((size_t)G4_ * H_ * 2);
  float* bias0 = (float*)alloc(G4_ * 4);
  float* bias1 = (float*)alloc(G4_ * 4);
  f16*   hbuf  = (f16*)alloc((size_t)2 * B_ * H_ * 2);
  float* cstb  = (float*)alloc((size_t)B_ * H_ * 4);
  unsigned* bars = (unsigned*)alloc(4096);

  hipMemsetAsync(bars, 0, 4096, stream);
  cvt_f32_f16<<<2048, 256, 0, stream>>>(x, x16, B_ * T_ * IN_);
  cvt_f32_f16<<<512, 256, 0, stream>>>(w_ih0, wih0h, G4_ * IN_);
  cvt_f32_f16<<<2048, 256, 0, stream>>>(w_hh0, whh0h, G4_ * H_);
  cvt_f32_f16<<<2048, 256, 0, stream>>>(w_ih1, wih1h, G4_ * H_);
  cvt_f32_f16<<<2048, 256, 0, stream>>>(w_hh1, whh1h, G4_ * H_);
  bias_comb<<<8, 256, 0, stream>>>(b_ih0, b_hh0, bias0, G4_);
  bias_comb<<<8, 256, 0, stream>>>(b_ih1, b_hh1, bias1, G4_);

  for (int c = 0; c < T_ / CH_; ++c) {
    gemm_g<<<dim3(B_, 16), 256, 0, stream>>>(x16, wih0h, bias0, gxbuf, IN_, c * CH_);
    scan_g<<<NG_ * NS_, 256, 0, stream>>>(gxbuf, whh0h, hbuf, cstb, out0, c * CH_,
                                          bars + (size_t)c * NG_);
  }
  for (int c = 0; c < T_ / CH_; ++c) {
    gemm_g<<<dim3(B_, 16), 256, 0, stream>>>(out0, wih1h, bias1, gxbuf, H_, c * CH_);
    scan_g<<<NG_ * NS_, 256, 0, stream>>>(gxbuf, whh1h, hbuf, cstb, nullptr, c * CH_,
                                          bars + (size_t)(8 + c) * NG_);
  }
  head_g<<<B_, 256, 0, stream>>>(hbuf + (size_t)B_ * H_, w1, b1, w2, b2, out);
}

// Round 2
// 5512.030 us; speedup vs baseline: 7.0456x; 7.0456x over previous
//
#include <hip/hip_runtime.h>
#include <stdint.h>

#define B_  256
#define T_  512
#define IN_ 64
#define H_  512
#define G4_ 2048
#define NC_ 64
#define H2_ 256
#define CH_ 64     // timestep chunk
#define NG_ 16     // batch groups (16 batch rows each)
#define NS_ 16     // gate slices  (32 h-cols each)

typedef _Float16 f16;
typedef __attribute__((ext_vector_type(4))) _Float16 f16x4;
typedef __attribute__((ext_vector_type(4))) float    f32x4;
typedef __attribute__((ext_vector_type(4))) unsigned int u32x4;

__device__ __forceinline__ float sigf(float x) { return 1.0f / (1.0f + __expf(-x)); }

// L3-coherent (cache-bypassing) access helpers — no L2 writeback/invalidate needed.
__device__ __forceinline__ void store_u32_l3(unsigned int* p, unsigned int v) {
  asm volatile("global_store_dword %0, %1, off sc0 sc1" :: "v"(p), "v"(v) : "memory");
}
__device__ __forceinline__ u32x4 load_u32x4_l3(const void* p) {
  u32x4 r;
  asm volatile("global_load_dwordx4 %0, %1, off sc0 sc1" : "=v"(r) : "v"(p) : "memory");
  return r;
}
__device__ __forceinline__ void wait_vm0() {
  asm volatile("s_waitcnt vmcnt(0)" ::: "memory");
}

// ---------------- prep kernels ----------------
__global__ void cvt_f32_f16(const float* __restrict__ s, f16* __restrict__ d, int n) {
  int i = blockIdx.x * blockDim.x + threadIdx.x;
  int st = gridDim.x * blockDim.x;
  for (; i < n; i += st) d[i] = (f16)s[i];
}

__global__ void bias_comb(const float* __restrict__ a, const float* __restrict__ b,
                          float* __restrict__ d, int n) {
  int i = blockIdx.x * blockDim.x + threadIdx.x;
  if (i < n) d[i] = a[i] + b[i];
}

// ---------------- gx GEMM:  out[tc][b][g] = A[b][t0+tc][:] . W[g][:] + bias[g] ----------------
__global__ __launch_bounds__(256, 2) void gemm_g(
    const f16* __restrict__ A, const f16* __restrict__ W,
    const float* __restrict__ bias, f16* __restrict__ out, int K, int t0) {
  __shared__ f16 As[64][40];
  __shared__ f16 Bs[128][40];
  const int b    = blockIdx.x;
  const int nblk = blockIdx.y;
  const int tid  = threadIdx.x;
  const int lane = tid & 63, wv = tid >> 6;
  const int l15 = lane & 15, hi = lane >> 4;
  const int mbase = (wv >> 1) * 32, nbase = (wv & 1) * 64;

  f32x4 acc[2][4] = {};
  const f16* Ab = A + ((size_t)b * T_ + t0) * K;
  const f16* Wb = W + (size_t)nblk * 128 * K;

  for (int kb = 0; kb < K; kb += 32) {
    {
      const int r = tid >> 2, ko = (tid & 3) * 8;
      *(uint4*)&As[r][ko] = *(const uint4*)(Ab + (size_t)r * K + kb + ko);
    }
    {
      const int r = tid >> 1, ko = (tid & 1) * 16;
      *(uint4*)&Bs[r][ko]     = *(const uint4*)(Wb + (size_t)r * K + kb + ko);
      *(uint4*)&Bs[r][ko + 8] = *(const uint4*)(Wb + (size_t)r * K + kb + ko + 8);
    }
    __syncthreads();
#pragma unroll
    for (int ks = 0; ks < 2; ++ks) {
      const f16x4 a0 = *(const f16x4*)&As[mbase + l15][ks * 16 + 4 * hi];
      const f16x4 a1 = *(const f16x4*)&As[mbase + 16 + l15][ks * 16 + 4 * hi];
#pragma unroll
      for (int nt = 0; nt < 4; ++nt) {
        const f16x4 bf = *(const f16x4*)&Bs[nbase + nt * 16 + l15][ks * 16 + 4 * hi];
        acc[0][nt] = __builtin_amdgcn_mfma_f32_16x16x16f16(a0, bf, acc[0][nt], 0, 0, 0);
        acc[1][nt] = __builtin_amdgcn_mfma_f32_16x16x16f16(a1, bf, acc[1][nt], 0, 0, 0);
      }
    }
    __syncthreads();
  }
#pragma unroll
  for (int mt = 0; mt < 2; ++mt)
#pragma unroll
    for (int nt = 0; nt < 4; ++nt) {
      const int n = nblk * 128 + nbase + nt * 16 + l15;
      const float bv = bias[n];
#pragma unroll
      for (int r = 0; r < 4; ++r) {
        const int ml = mbase + mt * 16 + 4 * hi + r;   // local timestep 0..63
        out[((size_t)ml * B_ + b) * G4_ + n] = (f16)(acc[mt][nt][r] + bv);
      }
    }
}

// ---------------- recurrent scan (one layer, CH_ steps) ----------------
// block (grp,sl): batch rows grp*16..+15, h-cols sl*32..+31
// Cross-WG h exchange through L3 (sc0 sc1 ops) + relaxed atomic flags. NO fences.
__global__ __launch_bounds__(256, 1) void scan_g(
    const f16* __restrict__ gx,    // [CH][B][2048]  (bias folded in)
    const f16* __restrict__ whh,   // [2048][512]
    f16* __restrict__ hbuf,        // [2][B][512]
    float* __restrict__ cst,       // [B][512]
    f16* __restrict__ outseq,      // [B][T][512] or nullptr
    int t0, unsigned* __restrict__ bar_base) {
  __shared__ f16 ht[16][520];      // row stride 1040B = 16B-aligned
  __shared__ float gl[16][132];

  const int grp = blockIdx.x >> 4, sl = blockIdx.x & 15;
  const int tid = threadIdx.x;
  const int lane = tid & 63, wv = tid >> 6;
  const int l15 = lane & 15, hi = lane >> 4;
  unsigned* bar = bar_base + grp * 16;   // 64B-padded flag slot

  // preload static W_hh fragments into registers: 2 N-tiles x 32 k-steps
  int gidx[2];
  f16x4 bfr[2][32];
#pragma unroll
  for (int nt = 0; nt < 2; ++nt) {
    const int lg = (wv * 2 + nt) * 16 + l15;                 // local gate 0..127
    const int grow = (lg >> 5) * H_ + sl * 32 + (lg & 31);   // global gate row
    gidx[nt] = grow;
    const f16* wp = whh + (size_t)grow * H_;
#pragma unroll
    for (int ks = 0; ks < 32; ++ks)
      bfr[nt][ks] = *(const f16x4*)(wp + ks * 16 + 4 * hi);
  }

  // each thread owns 2 adjacent (batch,row) cells of the 16x32 state tile
  const int q = tid * 2;
  const int bl = q >> 5;
  const int j0 = q & 31, j1 = j0 + 1;
  const size_t cbase = (size_t)(grp * 16 + bl) * H_ + sl * 32;
  float c0 = 0.f, c1 = 0.f;
  if (t0 != 0) { c0 = cst[cbase + j0]; c1 = cst[cbase + j1]; }

  const int hrow = tid >> 4;
  const int hcol = (tid & 15) * 32;

  for (int it = 0; it < CH_; ++it) {
    const int t = t0 + it;
    const int cur = t & 1;

    // init accumulators from precomputed gx (independent of h(t-1) -> before the wait)
    f32x4 acc[2];
    {
      const f16* gb = gx + ((size_t)it * B_ + grp * 16) * G4_;
#pragma unroll
      for (int nt = 0; nt < 2; ++nt)
#pragma unroll
        for (int r = 0; r < 4; ++r)
          acc[nt][r] = (float)gb[(size_t)(4 * hi + r) * G4_ + gidx[nt]];
    }

    // wait until all 16 WGs of this group have published h(t-1)
    if (tid == 0 && it != 0) {
      const unsigned tgt = (unsigned)it * NS_;
      while (__hip_atomic_load(bar, __ATOMIC_RELAXED, __HIP_MEMORY_SCOPE_AGENT) < tgt)
        __builtin_amdgcn_s_sleep(1);
    }
    __syncthreads();

    // stage h(t-1) tile into LDS (L3-coherent loads)
    if (t == 0) {
      u32x4 z = {0u, 0u, 0u, 0u};
#pragma unroll
      for (int u = 0; u < 4; ++u) *(u32x4*)&ht[hrow][hcol + u * 8] = z;
    } else {
      const f16* hs = hbuf + ((size_t)(cur ^ 1) * B_ + grp * 16 + hrow) * H_ + hcol;
      u32x4 r0 = load_u32x4_l3(hs);
      u32x4 r1 = load_u32x4_l3(hs + 8);
      u32x4 r2 = load_u32x4_l3(hs + 16);
      u32x4 r3 = load_u32x4_l3(hs + 24);
      wait_vm0();
      __builtin_amdgcn_sched_barrier(0);
      *(u32x4*)&ht[hrow][hcol]      = r0;
      *(u32x4*)&ht[hrow][hcol + 8]  = r1;
      *(u32x4*)&ht[hrow][hcol + 16] = r2;
      *(u32x4*)&ht[hrow][hcol + 24] = r3;
    }
    __syncthreads();

#pragma unroll
    for (int ks = 0; ks < 32; ++ks) {
      const f16x4 a = *(const f16x4*)&ht[l15][ks * 16 + 4 * hi];
      acc[0] = __builtin_amdgcn_mfma_f32_16x16x16f16(a, bfr[0][ks], acc[0], 0, 0, 0);
      acc[1] = __builtin_amdgcn_mfma_f32_16x16x16f16(a, bfr[1][ks], acc[1], 0, 0, 0);
    }

    __syncthreads();
#pragma unroll
    for (int nt = 0; nt < 2; ++nt) {
      const int col = (wv * 2 + nt) * 16 + l15;
#pragma unroll
      for (int r = 0; r < 4; ++r) gl[4 * hi + r][col] = acc[nt][r];
    }
    __syncthreads();

    const float gi0 = gl[bl][j0],      gi1 = gl[bl][j1];
    const float gf0 = gl[bl][32 + j0], gf1 = gl[bl][32 + j1];
    const float gg0 = gl[bl][64 + j0], gg1 = gl[bl][64 + j1];
    const float go0 = gl[bl][96 + j0], go1 = gl[bl][96 + j1];
    c0 = sigf(gf0) * c0 + sigf(gi0) * tanhf(gg0);
    c1 = sigf(gf1) * c1 + sigf(gi1) * tanhf(gg1);
    const float h0 = sigf(go0) * tanhf(c0);
    const float h1 = sigf(go1) * tanhf(c1);
    const f16 h0h = (f16)h0, h1h = (f16)h1;

    // publish h(t) through L3
    unsigned hp = ((unsigned)__builtin_bit_cast(unsigned short, h1h) << 16)
                |  (unsigned)__builtin_bit_cast(unsigned short, h0h);
    store_u32_l3((unsigned*)(hbuf + (size_t)cur * B_ * H_ + cbase + j0), hp);

    if (outseq) {
      f16* ow = outseq + ((size_t)(grp * 16 + bl) * T_ + t) * H_ + sl * 32;
      *(unsigned*)(ow + j0) = hp;   // plain store; consumed by next kernel launch
    }
    if (it == CH_ - 1) { cst[cbase + j0] = c0; cst[cbase + j1] = c1; }

    // signal: own stores drained to coherence point, then one relaxed add per WG
    if (it != CH_ - 1) {
      wait_vm0();
      __syncthreads();
      if (tid == 0)
        __hip_atomic_fetch_add(bar, 1u, __ATOMIC_RELAXED, __HIP_MEMORY_SCOPE_AGENT);
    }
  }
}

// ---------------- MLP head ----------------
__global__ void head_g(const f16* __restrict__ h1, const float* __restrict__ w1,
                       const float* __restrict__ b1, const float* __restrict__ w2,
                       const float* __restrict__ b2, float* __restrict__ out) {
  __shared__ float ft[512];
  __shared__ float hm[256];
  const int b = blockIdx.x, tid = threadIdx.x;
  ft[tid * 2]     = (float)h1[(size_t)b * H_ + tid * 2];
  ft[tid * 2 + 1] = (float)h1[(size_t)b * H_ + tid * 2 + 1];
  __syncthreads();
  {
    float d = b1[tid];
    const float* wr = w1 + (size_t)tid * H_;
#pragma unroll 8
    for (int k = 0; k < H_; ++k) d += ft[k] * wr[k];
    hm[tid] = fmaxf(d, 0.f);
  }
  __syncthreads();
  if (tid < NC_) {
    float d = b2[tid];
    const float* wr = w2 + (size_t)tid * H2_;
#pragma unroll 8
    for (int k = 0; k < H2_; ++k) d += hm[k] * wr[k];
    out[(size_t)b * NC_ + tid] = d;
  }
}

// ---------------- launcher ----------------
extern "C" void kernel_launch(void* const* d_in, const int* in_sizes, int n_in,
                              void* d_out, int out_size, void* d_ws, size_t ws_size,
                              hipStream_t stream) {
  const float* x     = (const float*)d_in[0];
  const float* w_ih0 = (const float*)d_in[1];
  const float* w_hh0 = (const float*)d_in[2];
  const float* b_ih0 = (const float*)d_in[3];
  const float* b_hh0 = (const float*)d_in[4];
  const float* w_ih1 = (const float*)d_in[5];
  const float* w_hh1 = (const float*)d_in[6];
  const float* b_ih1 = (const float*)d_in[7];
  const float* b_hh1 = (const float*)d_in[8];
  const float* w1    = (const float*)d_in[9];
  const float* b1    = (const float*)d_in[10];
  const float* w2    = (const float*)d_in[11];
  const float* b2    = (const float*)d_in[12];
  float* out = (float*)d_out;

  char* p = (char*)d_ws;
  auto alloc = [&](size_t bytes) { char* r = p; p += (bytes + 255) & ~(size_t)255; return r; };
  f16*   gxbuf = (f16*)alloc((size_t)CH_ * B_ * G4_ * 2);
  f16*   out0  = (f16*)alloc((size_t)B_ * T_ * H_ * 2);
  f16*   x16   = (f16*)alloc((size_t)B_ * T_ * IN_ * 2);
  f16*   wih0h = (f16*)alloc((size_t)G4_ * IN_ * 2);
  f16*   whh0h = (f16*)alloc((size_t)G4_ * H_ * 2);
  f16*   wih1h = (f16*)alloc((size_t)G4_ * H_ * 2);
  f16*   whh1h = (f16*)alloc((size_t)G4_ * H_ * 2);
  float* bias0 = (float*)alloc(G4_ * 4);
  float* bias1 = (float*)alloc(G4_ * 4);
  f16*   hbuf  = (f16*)alloc((size_t)2 * B_ * H_ * 2);
  float* cstb  = (float*)alloc((size_t)B_ * H_ * 4);
  unsigned* bars = (unsigned*)alloc(16 * NG_ * 64);

  hipMemsetAsync(bars, 0, 16 * NG_ * 64, stream);
  cvt_f32_f16<<<2048, 256, 0, stream>>>(x, x16, B_ * T_ * IN_);
  cvt_f32_f16<<<512, 256, 0, stream>>>(w_ih0, wih0h, G4_ * IN_);
  cvt_f32_f16<<<2048, 256, 0, stream>>>(w_hh0, whh0h, G4_ * H_);
  cvt_f32_f16<<<2048, 256, 0, stream>>>(w_ih1, wih1h, G4_ * H_);
  cvt_f32_f16<<<2048, 256, 0, stream>>>(w_hh1, whh1h, G4_ * H_);
  bias_comb<<<8, 256, 0, stream>>>(b_ih0, b_hh0, bias0, G4_);
  bias_comb<<<8, 256, 0, stream>>>(b_ih1, b_hh1, bias1, G4_);

  for (int c = 0; c < T_ / CH_; ++c) {
    gemm_g<<<dim3(B_, 16), 256, 0, stream>>>(x16, wih0h, bias0, gxbuf, IN_, c * CH_);
    scan_g<<<NG_ * NS_, 256, 0, stream>>>(gxbuf, whh0h, hbuf, cstb, out0, c * CH_,
                                          bars + (size_t)c * NG_ * 16);
  }
  for (int c = 0; c < T_ / CH_; ++c) {
    gemm_g<<<dim3(B_, 16), 256, 0, stream>>>(out0, wih1h, bias1, gxbuf, H_, c * CH_);
    scan_g<<<NG_ * NS_, 256, 0, stream>>>(gxbuf, whh1h, hbuf, cstb, nullptr, c * CH_,
                                          bars + (size_t)(8 + c) * NG_ * 16);
  }
  head_g<<<B_, 256, 0, stream>>>(hbuf + (size_t)B_ * H_, w1, b1, w2, b2, out);
}